// Round 5
// baseline (481.976 us; speedup 1.0000x reference)
//
#include <hip/hip_runtime.h>

#define BB 256
#define TT 512
#define CC 128
#define GPB 2                 // independent batch-groups per block
#define NBLK (BB / (16 * GPB))  // 8 blocks

typedef short short8 __attribute__((ext_vector_type(8)));
typedef float f32x4  __attribute__((ext_vector_type(4)));

__device__ __forceinline__ unsigned f2bf(float v) {   // f32 -> bf16 bits (RTNE)
    unsigned u = __float_as_uint(v);
    u += 0x7FFFu + ((u >> 16) & 1u);
    return u >> 16;
}
__device__ __forceinline__ unsigned pack2(float a, float b) {
    return f2bf(a) | (f2bf(b) << 16);
}
__device__ __forceinline__ unsigned umx(unsigned a, unsigned b) { return a > b ? a : b; }
__device__ __forceinline__ f32x4 expv4(f32x4 x) {
    return f32x4{__expf(x[0]), __expf(x[1]), __expf(x[2]), __expf(x[3])};
}

// Forward algorithm, exp domain, MFMA, latency-hidden by 2 independent
// batch-groups per block (2 waves/SIMD). 8 blocks x 512 threads.
// Group q (waves 4q..4q+3) owns batches [blk*32+16q, +16). Within a group:
// wave ws owns output states [32ws, 32ws+32); lane l: batch n=l&15, g=l>>4.
// E^T = exp(T)^T lives in VGPR A-fragments; alpha^T bounces through a
// swizzled double-buffered bf16 LDS tile (one raw barrier per step, vmcnt
// never drained so emission prefetches stay in flight).
__global__ __launch_bounds__(512, 1)
void crf_forward(const float* __restrict__ em_all,
                 const void* __restrict__ mask,
                 const float* __restrict__ transitions,
                 float* __restrict__ log_den)
{
    const int tid = threadIdx.x;
    const int l = tid & 63, w = tid >> 6;   // wave 0..7
    const int q = w >> 2, ws = w & 3;       // group, wave-in-group
    const int n = l & 15, g = l >> 4;
    const int bbase = blockIdx.x * (16 * GPB) + 16 * q;

    __shared__ __align__(16) unsigned abuf[2][GPB][16 * 64]; // bf16 alpha
    __shared__ float finred[GPB][4][16];
    __shared__ int lenred[2 * GPB * 4];

    // u32 index of (batch nn, state s); XOR-swizzle bits>=3 of s so the 16
    // same-g lanes of a wave spread across bank-pairs (b64 write ~2-way).
    auto aidx = [](int nn, int s) -> int {
        return nn * 64 + ((s ^ ((nn & 15) << 3)) >> 1);
    };

    // ---- mask dtype + per-batch length (prefix-true mask) ----
    const unsigned char* mb = (const unsigned char*)mask;
    const bool is_u8 = (mb[1] != 0);    // lengths >= 256 so mask[0][1] is set
    int cnt = 0;
    const int rowbase = (bbase + n) * TT + g * 128;  // lane counts a quarter-row
    if (is_u8) {
        const uint4* mp = (const uint4*)(mb + rowbase);
        #pragma unroll
        for (int k = 0; k < 8; ++k) {
            const uint4 v = mp[k];
            const unsigned s4 = (v.x & 0x01010101u) + (v.y & 0x01010101u)
                              + (v.z & 0x01010101u) + (v.w & 0x01010101u);
            cnt += (int)((s4 * 0x01010101u) >> 24);
        }
    } else {
        const uint4* mp = (const uint4*)((const unsigned*)mask + rowbase);
        #pragma unroll
        for (int k = 0; k < 32; ++k) {
            const uint4 v = mp[k];
            cnt += (v.x ? 1 : 0) + (v.y ? 1 : 0) + (v.z ? 1 : 0) + (v.w ? 1 : 0);
        }
    }
    cnt += __shfl_xor(cnt, 16); cnt += __shfl_xor(cnt, 32);
    const int len_n = cnt;                 // this lane's batch length
    int lmx = len_n;
    #pragma unroll
    for (int off = 1; off <= 8; off <<= 1) lmx = max(lmx, __shfl_xor(lmx, off));
    if (l == 0) lenred[w] = lmx;           // block-uniform loop bound
    __syncthreads();
    int len_max = lenred[0];
    #pragma unroll
    for (int k = 1; k < 8; ++k) len_max = max(len_max, lenred[k]);

    // ---- A-fragments: A[m,k] = E^T[m,k] = exp(T[k][m]) ----
    // lane l, elem e of tile (mt,kt): m = 32ws+16mt+n, k = 32kt+8g+e
    short8 afr[2][4];
    #pragma unroll
    for (int mt = 0; mt < 2; ++mt) {
        #pragma unroll
        for (int kt = 0; kt < 4; ++kt) {
            short8 a;
            #pragma unroll
            for (int e = 0; e < 8; ++e) {
                const int k = 32 * kt + 8 * g + e;
                const int m = 32 * ws + 16 * mt + n;
                a[e] = (short)f2bf(__expf(transitions[k * CC + m]));
            }
            afr[mt][kt] = a;
        }
    }

    // ---- t=0 init: alpha = exp(emissions[:,0,:]) ----
    const float* emb = em_all + (size_t)(bbase + n) * TT * CC;
    const int s0 = 32 * ws + 4 * g;        // lane's first state (mt=0); mt=1 at +16
    float av[8]; unsigned pk[4];
    {
        const f32x4 e0 = *(const f32x4*)&emb[s0];
        const f32x4 e1 = *(const f32x4*)&emb[s0 + 16];
        #pragma unroll
        for (int i = 0; i < 4; ++i) { av[i] = __expf(e0[i]); av[4 + i] = __expf(e1[i]); }
        pk[0] = pack2(av[0], av[1]); pk[1] = pack2(av[2], av[3]);
        pk[2] = pack2(av[4], av[5]); pk[3] = pack2(av[6], av[7]);
        *(uint2*)&abuf[0][q][aidx(n, s0)]      = make_uint2(pk[0], pk[1]);
        *(uint2*)&abuf[0][q][aidx(n, s0 + 16)] = make_uint2(pk[2], pk[3]);
    }
    // emission prefetch, 2 steps ahead, ALREADY exponentiated (off the
    // post-MFMA critical path)
    f32x4 emc0 = expv4(*(const f32x4*)&emb[(size_t)1 * CC + s0]);
    f32x4 emc1 = expv4(*(const f32x4*)&emb[(size_t)1 * CC + s0 + 16]);
    f32x4 emn0 = expv4(*(const f32x4*)&emb[(size_t)2 * CC + s0]);
    f32x4 emn1 = expv4(*(const f32x4*)&emb[(size_t)2 * CC + s0 + 16]);
    float logoff = 0.f;

    asm volatile("s_waitcnt lgkmcnt(0)\n\ts_barrier" ::: "memory");

    for (int t = 1; t < len_max; ++t) {
        // raw emission load for t+2 (exp applied after MFMA issue)
        const int tf = (t + 2 < TT) ? (t + 2) : (TT - 1);
        const f32x4 ef0 = *(const f32x4*)&emb[(size_t)tf * CC + s0];
        const f32x4 ef1 = *(const f32x4*)&emb[(size_t)tf * CC + s0 + 16];

        // B-fragments: alpha^T[k, n], k = 32kt+8g+e, from buf[(t+1)&1]
        const unsigned* rbuf = abuf[(t + 1) & 1][q];
        uint4 rbu[4];
        #pragma unroll
        for (int kt = 0; kt < 4; ++kt)
            rbu[kt] = *(const uint4*)&rbuf[aidx(n, 32 * kt + 8 * g)];

        f32x4 acc0 = {0.f, 0.f, 0.f, 0.f}, acc1 = {0.f, 0.f, 0.f, 0.f};
        #pragma unroll
        for (int kt = 0; kt < 4; ++kt) {
            const short8 bf = __builtin_bit_cast(short8, rbu[kt]);
            acc0 = __builtin_amdgcn_mfma_f32_16x16x32_bf16(afr[0][kt], bf, acc0, 0, 0, 0);
            acc1 = __builtin_amdgcn_mfma_f32_16x16x32_bf16(afr[1][kt], bf, acc1, 0, 0, 0);
        }

        // renorm every 4 steps: per-batch max of the bf16 alpha just read
        // (identical data in all 4 waves of the group -> identical scale)
        int ex = 0; float scale = 1.0f;
        if ((t & 3) == 0) {
            unsigned mx = 0;
            #pragma unroll
            for (int kt = 0; kt < 4; ++kt) {
                mx = umx(mx, rbu[kt].x & 0xFFFF0000u); mx = umx(mx, rbu[kt].x << 16);
                mx = umx(mx, rbu[kt].y & 0xFFFF0000u); mx = umx(mx, rbu[kt].y << 16);
                mx = umx(mx, rbu[kt].z & 0xFFFF0000u); mx = umx(mx, rbu[kt].z << 16);
                mx = umx(mx, rbu[kt].w & 0xFFFF0000u); mx = umx(mx, rbu[kt].w << 16);
            }
            mx = umx(mx, (unsigned)__shfl_xor((int)mx, 16));
            mx = umx(mx, (unsigned)__shfl_xor((int)mx, 32));
            ex = (int)((mx >> 23) & 255u) - 127;
            scale = __uint_as_float((unsigned)(127 - ex) << 23);   // 2^-ex
        }

        const bool active = (t < len_n);
        float nv[8];
        #pragma unroll
        for (int i = 0; i < 4; ++i) {
            nv[i]     = acc0[i] * emc0[i] * scale;
            nv[4 + i] = acc1[i] * emc1[i] * scale;
        }
        if (active) {
            #pragma unroll
            for (int i = 0; i < 8; ++i) av[i] = nv[i];
            pk[0] = pack2(av[0], av[1]); pk[1] = pack2(av[2], av[3]);
            pk[2] = pack2(av[4], av[5]); pk[3] = pack2(av[6], av[7]);
            logoff += (float)ex * 0.69314718f;
        }
        emc0 = emn0; emc1 = emn1; emn0 = expv4(ef0); emn1 = expv4(ef1);

        // publish alpha for t+1 (frozen lanes rewrite their held value)
        unsigned* wbuf = abuf[t & 1][q];
        *(uint2*)&wbuf[aidx(n, s0)]      = make_uint2(pk[0], pk[1]);
        *(uint2*)&wbuf[aidx(n, s0 + 16)] = make_uint2(pk[2], pk[3]);

        asm volatile("s_waitcnt lgkmcnt(0)\n\ts_barrier" ::: "memory");
    }

    // ---- log_den[b] = logoff + log(sum over states) ----
    float s = ((av[0] + av[1]) + (av[2] + av[3])) + ((av[4] + av[5]) + (av[6] + av[7]));
    s += __shfl_xor(s, 16); s += __shfl_xor(s, 32);   // over g within wave
    if (l < 16) finred[q][ws][l] = s;                 // l==n here
    __syncthreads();
    if (ws == 0 && l < 16) {
        const float tot = finred[q][0][l] + finred[q][1][l]
                        + finred[q][2][l] + finred[q][3][l];
        log_den[bbase + l] = logoff + __logf(tot);
    }
}

__device__ __forceinline__ bool mask_at(const void* mask, bool is_u8, int idx) {
    if (is_u8) return ((const unsigned char*)mask)[idx] != 0;
    return ((const int*)mask)[idx] != 0;
}

// Gold-path score: sum of masked emissions at tags + masked pair transitions.
__global__ __launch_bounds__(256)
void crf_num(const float* __restrict__ em_all,
             const int* __restrict__ tags,
             const void* __restrict__ mask,
             const float* __restrict__ transitions,
             float* __restrict__ log_num)
{
    const int b = blockIdx.x;
    const int j = threadIdx.x;
    const int lane = j & 63;
    const int wid = j >> 6;
    __shared__ float redf[4];

    const unsigned char* mb = (const unsigned char*)mask;
    const bool is_u8 = (mb[1] != 0);

    const float* em = em_all + (size_t)b * TT * CC;
    const int* tg = tags + b * TT;

    float s = 0.f;
    for (int t = j; t < TT; t += 256) {
        if (mask_at(mask, is_u8, b * TT + t)) {
            s += em[t * CC + tg[t]];
            if (t >= 1 && mask_at(mask, is_u8, b * TT + t - 1))
                s += transitions[tg[t - 1] * CC + tg[t]];
        }
    }
    #pragma unroll
    for (int off = 32; off; off >>= 1) s += __shfl_xor(s, off);
    if (lane == 0) redf[wid] = s;
    __syncthreads();
    if (j == 0) log_num[b] = redf[0] + redf[1] + redf[2] + redf[3];
}

__global__ __launch_bounds__(256)
void crf_final(const float* __restrict__ log_den,
               const float* __restrict__ log_num,
               float* __restrict__ out)
{
    const int j = threadIdx.x;   // one thread per batch, B == 256
    const int lane = j & 63;
    const int wid = j >> 6;
    __shared__ float redf[4];
    float v = log_den[j] - log_num[j];
    #pragma unroll
    for (int off = 32; off; off >>= 1) v += __shfl_xor(v, off);
    if (lane == 0) redf[wid] = v;
    __syncthreads();
    if (j == 0) out[0] = (redf[0] + redf[1] + redf[2] + redf[3]) * (1.0f / BB);
}

extern "C" void kernel_launch(void* const* d_in, const int* in_sizes, int n_in,
                              void* d_out, int out_size, void* d_ws, size_t ws_size,
                              hipStream_t stream) {
    const float* emissions   = (const float*)d_in[0];
    const int*   tags        = (const int*)d_in[1];
    const void*  mask        = d_in[2];
    const float* transitions = (const float*)d_in[3];
    float* out = (float*)d_out;

    float* log_den = (float*)d_ws;
    float* log_num = log_den + BB;

    crf_forward<<<NBLK, 512, 0, stream>>>(emissions, mask, transitions, log_den);
    crf_num<<<BB, 256, 0, stream>>>(emissions, tags, mask, transitions, log_num);
    crf_final<<<1, 256, 0, stream>>>(log_den, log_num, out);
}

// Round 6
// 267.100 us; speedup vs baseline: 1.8045x; 1.8045x over previous
//
#include <hip/hip_runtime.h>

#define BB 256
#define TT 512
#define CC 128
#define G  16            // batches per block
#define NBLK (BB / G)    // 16 blocks

typedef short short8 __attribute__((ext_vector_type(8)));
typedef float f32x4  __attribute__((ext_vector_type(4)));

__device__ __forceinline__ unsigned f2bf(float v) {   // f32 -> bf16 bits (RTNE)
    unsigned u = __float_as_uint(v);
    u += 0x7FFFu + ((u >> 16) & 1u);
    return u >> 16;
}
__device__ __forceinline__ unsigned pack2(float a, float b) {
    return f2bf(a) | (f2bf(b) << 16);
}
__device__ __forceinline__ unsigned umx(unsigned a, unsigned b) { return a > b ? a : b; }
__device__ __forceinline__ f32x4 expv4(f32x4 x) {
    return f32x4{__expf(x[0]), __expf(x[1]), __expf(x[2]), __expf(x[3])};
}

// Forward algorithm, exp domain, MFMA. 16 blocks x 4 waves; block handles 16
// batches. E^T is the (static) A-operand held in VGPR fragments; alpha^T is
// the B-operand, bounced through a swizzled 8KB double-buffered LDS tile in
// bf16. Wave w owns output states [32w,32w+32); lane l owns batch n=l&15.
// Emission loads run a depth-4 register queue: raw load issued at iter t is
// exp'd at t+2 and consumed at t+3, so the vmcnt wait lands ~2 full
// iterations after issue (hides L3/HBM latency; vmcnt never drained at the
// barrier -- raw lgkmcnt(0)+s_barrier only).
__global__ __launch_bounds__(256, 1)
void crf_forward(const float* __restrict__ em_all,
                 const void* __restrict__ mask,
                 const float* __restrict__ transitions,
                 float* __restrict__ log_den)
{
    const int tid = threadIdx.x;
    const int l = tid & 63, w = tid >> 6;
    const int n = l & 15, g = l >> 4;
    const int bbase = blockIdx.x * G;

    __shared__ __align__(16) unsigned abuf[2][16 * 64];  // bf16 alpha, 2 buffers
    __shared__ float finred[4][16];

    // u32 index of (batch nn, state s); XOR-swizzle bits>=3 of s so the 16
    // same-g lanes of a wave spread across bank-pairs/quads (~2-way max).
    auto aidx = [](int nn, int s) -> int {
        return nn * 64 + ((s ^ ((nn & 15) << 3)) >> 1);
    };

    // ---- mask dtype + per-batch length (prefix-true mask) ----
    const unsigned char* mb = (const unsigned char*)mask;
    const bool is_u8 = (mb[1] != 0);    // lengths >= 256 so mask[0][1] is set
    int cnt = 0;
    const int rowbase = (bbase + n) * TT + g * 128;   // lane counts a quarter-row
    if (is_u8) {
        const uint4* mp = (const uint4*)(mb + rowbase);
        #pragma unroll
        for (int k = 0; k < 8; ++k) {
            const uint4 v = mp[k];
            const unsigned s4 = (v.x & 0x01010101u) + (v.y & 0x01010101u)
                              + (v.z & 0x01010101u) + (v.w & 0x01010101u);
            cnt += (int)((s4 * 0x01010101u) >> 24);
        }
    } else {
        const uint4* mp = (const uint4*)((const unsigned*)mask + rowbase);
        #pragma unroll
        for (int k = 0; k < 32; ++k) {
            const uint4 v = mp[k];
            cnt += (v.x ? 1 : 0) + (v.y ? 1 : 0) + (v.z ? 1 : 0) + (v.w ? 1 : 0);
        }
    }
    cnt += __shfl_xor(cnt, 16); cnt += __shfl_xor(cnt, 32);
    const int len_n = cnt;                 // this lane's batch length
    int lmx = len_n;
    #pragma unroll
    for (int off = 1; off <= 8; off <<= 1) lmx = max(lmx, __shfl_xor(lmx, off));
    const int len_max = lmx;               // uniform loop bound

    // ---- A-fragments: A[m,k] = E^T[m,k] = exp(T[k][m]) ----
    // lane l, elem e of tile (mt,kt): m = 32w+16mt+n, k = 32kt+8g+e
    short8 afr[2][4];
    #pragma unroll
    for (int mt = 0; mt < 2; ++mt) {
        #pragma unroll
        for (int kt = 0; kt < 4; ++kt) {
            short8 a;
            #pragma unroll
            for (int e = 0; e < 8; ++e) {
                const int k = 32 * kt + 8 * g + e;
                const int m = 32 * w + 16 * mt + n;
                a[e] = (short)f2bf(__expf(transitions[k * CC + m]));
            }
            afr[mt][kt] = a;
        }
    }

    // ---- t=0 init: alpha = exp(emissions[:,0,:]) ----
    const float* emb = em_all + (size_t)(bbase + n) * TT * CC;
    const int s0 = 32 * w + 4 * g;         // lane's first state (mt=0); mt=1 at +16
    float av[8]; unsigned pk[4];
    {
        const f32x4 e0 = *(const f32x4*)&emb[s0];
        const f32x4 e1 = *(const f32x4*)&emb[s0 + 16];
        #pragma unroll
        for (int i = 0; i < 4; ++i) { av[i] = __expf(e0[i]); av[4 + i] = __expf(e1[i]); }
        pk[0] = pack2(av[0], av[1]); pk[1] = pack2(av[2], av[3]);
        pk[2] = pack2(av[4], av[5]); pk[3] = pack2(av[6], av[7]);
        *(uint2*)&abuf[0][aidx(n, s0)]      = make_uint2(pk[0], pk[1]);
        *(uint2*)&abuf[0][aidx(n, s0 + 16)] = make_uint2(pk[2], pk[3]);
    }

    // ---- emission register queue ----
    // ec = exp(em[t]) for current step, en = exp(em[t+1]),
    // r1 = raw em[t+2], r2 = raw em[t+3]; at iter t we issue em[t+4].
    f32x4 ec0 = expv4(*(const f32x4*)&emb[(size_t)min(1, TT - 1) * CC + s0]);
    f32x4 ec1 = expv4(*(const f32x4*)&emb[(size_t)min(1, TT - 1) * CC + s0 + 16]);
    f32x4 en0 = expv4(*(const f32x4*)&emb[(size_t)min(2, TT - 1) * CC + s0]);
    f32x4 en1 = expv4(*(const f32x4*)&emb[(size_t)min(2, TT - 1) * CC + s0 + 16]);
    f32x4 r10 = *(const f32x4*)&emb[(size_t)min(3, TT - 1) * CC + s0];
    f32x4 r11 = *(const f32x4*)&emb[(size_t)min(3, TT - 1) * CC + s0 + 16];
    f32x4 r20 = *(const f32x4*)&emb[(size_t)min(4, TT - 1) * CC + s0];
    f32x4 r21 = *(const f32x4*)&emb[(size_t)min(4, TT - 1) * CC + s0 + 16];
    float logoff = 0.f;

    asm volatile("s_waitcnt lgkmcnt(0)\n\ts_barrier" ::: "memory");

    for (int t = 1; t < len_max; ++t) {
        // issue raw emission load for t+4 (consumed 3 iterations from now)
        const int tf = (t + 4 < TT) ? (t + 4) : (TT - 1);
        const f32x4 ld0 = *(const f32x4*)&emb[(size_t)tf * CC + s0];
        const f32x4 ld1 = *(const f32x4*)&emb[(size_t)tf * CC + s0 + 16];

        // B-fragments: alpha^T[k, n], k = 32kt+8g+e, from buf[(t+1)&1]
        const unsigned* rbuf = abuf[(t + 1) & 1];
        uint4 rbu[4];
        #pragma unroll
        for (int kt = 0; kt < 4; ++kt)
            rbu[kt] = *(const uint4*)&rbuf[aidx(n, 32 * kt + 8 * g)];

        f32x4 acc0 = {0.f, 0.f, 0.f, 0.f}, acc1 = {0.f, 0.f, 0.f, 0.f};
        #pragma unroll
        for (int kt = 0; kt < 4; ++kt) {
            const short8 bf = __builtin_bit_cast(short8, rbu[kt]);
            acc0 = __builtin_amdgcn_mfma_f32_16x16x32_bf16(afr[0][kt], bf, acc0, 0, 0, 0);
            acc1 = __builtin_amdgcn_mfma_f32_16x16x32_bf16(afr[1][kt], bf, acc1, 0, 0, 0);
        }

        // renorm every 4 steps: per-batch max of the bf16 alpha just read
        // (identical data in all 4 waves -> identical exact power-of-2 scale)
        int ex = 0; float scale = 1.0f;
        if ((t & 3) == 0) {
            unsigned mx = 0;
            #pragma unroll
            for (int kt = 0; kt < 4; ++kt) {
                mx = umx(mx, rbu[kt].x & 0xFFFF0000u); mx = umx(mx, rbu[kt].x << 16);
                mx = umx(mx, rbu[kt].y & 0xFFFF0000u); mx = umx(mx, rbu[kt].y << 16);
                mx = umx(mx, rbu[kt].z & 0xFFFF0000u); mx = umx(mx, rbu[kt].z << 16);
                mx = umx(mx, rbu[kt].w & 0xFFFF0000u); mx = umx(mx, rbu[kt].w << 16);
            }
            mx = umx(mx, (unsigned)__shfl_xor((int)mx, 16));
            mx = umx(mx, (unsigned)__shfl_xor((int)mx, 32));
            ex = (int)((mx >> 23) & 255u) - 127;
            scale = __uint_as_float((unsigned)(127 - ex) << 23);   // 2^-ex
        }

        const bool active = (t < len_n);
        float nv[8];
        #pragma unroll
        for (int i = 0; i < 4; ++i) {
            nv[i]     = acc0[i] * ec0[i] * scale;
            nv[4 + i] = acc1[i] * ec1[i] * scale;
        }
        if (active) {
            #pragma unroll
            for (int i = 0; i < 8; ++i) av[i] = nv[i];
            pk[0] = pack2(av[0], av[1]); pk[1] = pack2(av[2], av[3]);
            pk[2] = pack2(av[4], av[5]); pk[3] = pack2(av[6], av[7]);
            logoff += (float)ex * 0.69314718f;
        }

        // shift the emission queue: exp the raw loaded 2 iterations ago
        ec0 = en0; ec1 = en1;
        en0 = expv4(r10); en1 = expv4(r11);
        r10 = r20; r11 = r21;
        r20 = ld0; r21 = ld1;

        // publish alpha for t+1 (frozen lanes rewrite their held value)
        unsigned* wbuf = abuf[t & 1];
        *(uint2*)&wbuf[aidx(n, s0)]      = make_uint2(pk[0], pk[1]);
        *(uint2*)&wbuf[aidx(n, s0 + 16)] = make_uint2(pk[2], pk[3]);

        asm volatile("s_waitcnt lgkmcnt(0)\n\ts_barrier" ::: "memory");
    }

    // ---- log_den[b] = logoff + log(sum over states) ----
    float s = ((av[0] + av[1]) + (av[2] + av[3])) + ((av[4] + av[5]) + (av[6] + av[7]));
    s += __shfl_xor(s, 16); s += __shfl_xor(s, 32);   // over g within wave
    if (l < 16) finred[w][l] = s;                     // l==n here
    __syncthreads();
    if (w == 0 && l < 16) {
        const float tot = finred[0][l] + finred[1][l] + finred[2][l] + finred[3][l];
        log_den[bbase + l] = logoff + __logf(tot);
    }
}

__device__ __forceinline__ bool mask_at(const void* mask, bool is_u8, int idx) {
    if (is_u8) return ((const unsigned char*)mask)[idx] != 0;
    return ((const int*)mask)[idx] != 0;
}

// Gold-path score: sum of masked emissions at tags + masked pair transitions.
__global__ __launch_bounds__(256)
void crf_num(const float* __restrict__ em_all,
             const int* __restrict__ tags,
             const void* __restrict__ mask,
             const float* __restrict__ transitions,
             float* __restrict__ log_num)
{
    const int b = blockIdx.x;
    const int j = threadIdx.x;
    const int lane = j & 63;
    const int wid = j >> 6;
    __shared__ float redf[4];

    const unsigned char* mb = (const unsigned char*)mask;
    const bool is_u8 = (mb[1] != 0);

    const float* em = em_all + (size_t)b * TT * CC;
    const int* tg = tags + b * TT;

    float s = 0.f;
    for (int t = j; t < TT; t += 256) {
        if (mask_at(mask, is_u8, b * TT + t)) {
            s += em[t * CC + tg[t]];
            if (t >= 1 && mask_at(mask, is_u8, b * TT + t - 1))
                s += transitions[tg[t - 1] * CC + tg[t]];
        }
    }
    #pragma unroll
    for (int off = 32; off; off >>= 1) s += __shfl_xor(s, off);
    if (lane == 0) redf[wid] = s;
    __syncthreads();
    if (j == 0) log_num[b] = redf[0] + redf[1] + redf[2] + redf[3];
}

__global__ __launch_bounds__(256)
void crf_final(const float* __restrict__ log_den,
               const float* __restrict__ log_num,
               float* __restrict__ out)
{
    const int j = threadIdx.x;   // one thread per batch, B == 256
    const int lane = j & 63;
    const int wid = j >> 6;
    __shared__ float redf[4];
    float v = log_den[j] - log_num[j];
    #pragma unroll
    for (int off = 32; off; off >>= 1) v += __shfl_xor(v, off);
    if (lane == 0) redf[wid] = v;
    __syncthreads();
    if (j == 0) out[0] = (redf[0] + redf[1] + redf[2] + redf[3]) * (1.0f / BB);
}

extern "C" void kernel_launch(void* const* d_in, const int* in_sizes, int n_in,
                              void* d_out, int out_size, void* d_ws, size_t ws_size,
                              hipStream_t stream) {
    const float* emissions   = (const float*)d_in[0];
    const int*   tags        = (const int*)d_in[1];
    const void*  mask        = d_in[2];
    const float* transitions = (const float*)d_in[3];
    float* out = (float*)d_out;

    float* log_den = (float*)d_ws;
    float* log_num = log_den + BB;

    crf_forward<<<NBLK, 256, 0, stream>>>(emissions, mask, transitions, log_den);
    crf_num<<<BB, 256, 0, stream>>>(emissions, tags, mask, transitions, log_num);
    crf_final<<<1, 256, 0, stream>>>(log_den, log_num, out);
}